// Round 3
// baseline (728.427 us; speedup 1.0000x reference)
//
#include <hip/hip_runtime.h>
#include <stdint.h>

// ---------------------------------------------------------------------------
// BiGRU + LayerNorm for MI355X (gfx950)
// kx: X fp32 -> bf16 (padded K 968->992), once
// k0: convert/scale weights to bf16 (log2e folded in; n-gate gets 2*log2e);
//     b_hh_r / b_hh_z FOLDED into the k1 bias (additive in pre-acts).
// k1: xp = x @ W_ih^T + b_ih(+b_hh_{r,z})  (m97-style global_load_lds x16B)
// k2: serial GRU scan, 8 WGs x 4 waves (256 thr). Each wave owns 32 output
//     cols (2 col-groups x 3 gates = 6 MFMA tiles, 4-deep K chains).
//     Halves LDS h-broadcast traffic vs 8-wave layout; col-group-0 gate math
//     overlaps col-group-1 MFMA in the same wave. Raw s_barrier, no vmcnt
//     drain; PF=2 register ring for gi.
// k3: LayerNorm (unbiased std, clamp 1e-6), in place on d_out
// ---------------------------------------------------------------------------

#define LOG2E 1.4426950408889634f
#define TT 512
#define D_IN 968
#define KP 992
#define NOUT 768
#define HID 128

typedef __attribute__((ext_vector_type(8))) short short8;
typedef __attribute__((ext_vector_type(4))) float f32x4;
typedef __attribute__((ext_vector_type(4))) unsigned int u32x4;
typedef __attribute__((ext_vector_type(2))) unsigned int u32x2;

__device__ __forceinline__ unsigned short f2bf(float f) {
  unsigned u = __builtin_bit_cast(unsigned, f);
  u += 0x7FFFu + ((u >> 16) & 1u);   // RTNE
  return (unsigned short)(u >> 16);
}
__device__ __forceinline__ unsigned pack2bf(float a, float b) {
  return (unsigned)f2bf(a) | ((unsigned)f2bf(b) << 16);
}
__device__ __forceinline__ float exp2_(float x) { return __builtin_amdgcn_exp2f(x); }
__device__ __forceinline__ float rcp_(float x)  { return __builtin_amdgcn_rcpf(x); }

__device__ __forceinline__ void async_load16(const void* g, void* l) {
  __builtin_amdgcn_global_load_lds(
      (const __attribute__((address_space(1))) unsigned int*)g,
      (__attribute__((address_space(3))) unsigned int*)l, 16, 0, 0);
}

// workgroup barrier that does NOT drain vmcnt (only LDS visibility).
__device__ __forceinline__ void wg_barrier_lds() {
  asm volatile("s_waitcnt lgkmcnt(0)\n\ts_barrier" ::: "memory");
}

// ws layout
#define WIH_BYTES (NOUT * KP * 2)            // 1,523,712
#define WHH_BYTES (NOUT * HID * 2)           // 196,608
#define BIAS_BYTES 3072
#define BASE_OFF (WIH_BYTES + WHH_BYTES + BIAS_BYTES)  // 1,723,392 (256-aligned)
#define XBF_BYTES ((size_t)32768 * KP * 2)   // 65,011,712
#define XP_BYTES ((size_t)32768 * NOUT * 4)  // 100,663,296

// ---------------------------------------------------------------- kx: X->bf16
__global__ __launch_bounds__(256) void kx_convert(const float* __restrict__ X,
                                                  unsigned short* __restrict__ Xb) {
  const long row = blockIdx.x;
  const int t = threadIdx.x;  // chunk of 4 cols; 968/4 = 242 full chunks
  if (t < 242) {
    f32x4 v = *(const f32x4*)(X + row * D_IN + t * 4);
    u32x2 p = {pack2bf(v.x, v.y), pack2bf(v.z, v.w)};
    *(u32x2*)(Xb + row * KP + t * 4) = p;
  } else if (t < 248) {
    *(u32x2*)(Xb + row * KP + t * 4) = (u32x2){0, 0};  // zero-pad 968..991
  }
}

// ---------------------------------------------------------------- K0 convert
__global__ __launch_bounds__(256) void k0_convert(
    const float* __restrict__ wihf, const float* __restrict__ whhf,
    const float* __restrict__ bihf, const float* __restrict__ wihb,
    const float* __restrict__ whhb, const float* __restrict__ bihb,
    const float* __restrict__ bhhf, const float* __restrict__ bhhb,
    unsigned short* __restrict__ wih16, unsigned short* __restrict__ whh16,
    float* __restrict__ bias_s) {
  int blk = blockIdx.x, tid = threadIdx.x;
  if (blk < NOUT) {
    int n = blk;
    float sc = ((n % 384) < 256) ? LOG2E : 2.0f * LOG2E;
    const float* src = (n < 384) ? (wihf + (long)n * D_IN) : (wihb + (long)(n - 384) * D_IN);
    for (int c = 0; c < 4; c++) {
      int k = c * 256 + tid;
      if (k < KP) {
        float v = (k < D_IN) ? src[k] * sc : 0.0f;
        wih16[(long)n * KP + k] = f2bf(v);
      }
    }
  } else if (blk < NOUT + 96) {
    int e0 = ((blk - NOUT) * 256 + tid) * 4;
    for (int i = 0; i < 4; i++) {
      int e = e0 + i;
      int m = e >> 7, k = e & 127;
      float sc = ((m % 384) < 256) ? LOG2E : 2.0f * LOG2E;
      float v = (m < 384) ? whhf[m * HID + k] : whhb[(m - 384) * HID + k];
      whh16[e] = f2bf(v * sc);
    }
  } else {
    // bias: r/z gates get (b_ih + b_hh)*log2e (b_hh folded); n gate b_ih*2log2e
    for (int c = 0; c < 3; c++) {
      int n = c * 256 + tid;
      if (n < NOUT) {
        int g = (n % 384) >> 7;  // 0=r, 1=z, 2=n
        float sc = (g < 2) ? LOG2E : 2.0f * LOG2E;
        float bi = (n < 384) ? bihf[n] : bihb[n - 384];
        float bh = (n < 384) ? bhhf[n] : bhhb[n - 384];
        float v = (g < 2) ? (bi + bh) : bi;
        bias_s[n] = v * sc;
      }
    }
  }
}

// ---------------------------------------------------------------- K1 fast GEMM
__global__ __launch_bounds__(256, 2) void k1_gemm_fast(
    const unsigned short* __restrict__ Xb, const unsigned short* __restrict__ W,
    const float* __restrict__ bias_s, float* __restrict__ XP) {
  __shared__ unsigned short As[128 * 32];
  __shared__ unsigned short Bs[128 * 32];

  const int tid = threadIdx.x;
  const int lane = tid & 63, w = tid >> 6;
  const int q = lane >> 4, l15 = lane & 15;
  const int wr = w >> 1, wc = w & 1;
  const int nt = blockIdx.x;   // 0..5 fast -> consecutive WGs share A-tile (L2)
  const int mt = blockIdx.y;   // 0..255
  const long R0 = (long)mt * 128;
  const int C0 = nt * 128;

  f32x4 acc[4][4];
#pragma unroll
  for (int i = 0; i < 4; i++)
#pragma unroll
    for (int j = 0; j < 4; j++) acc[i][j] = {0.f, 0.f, 0.f, 0.f};

  for (int it = 0; it < 31; it++) {
    const int k0 = it * 32;
#pragma unroll
    for (int c = 0; c < 2; c++) {
      int idx = c * 256 + w * 64 + lane;
      int row = idx >> 2, koff = (idx & 3) * 8;
      async_load16(Xb + (R0 + row) * KP + k0 + koff,
                   ((char*)As) + (c * 256 + w * 64) * 16);
      async_load16(W + (long)(C0 + row) * KP + k0 + koff,
                   ((char*)Bs) + (c * 256 + w * 64) * 16);
    }
    __syncthreads();  // drains vmcnt -> global_load_lds complete (m97 pattern)
    short8 af[4], bf[4];
#pragma unroll
    for (int i = 0; i < 4; i++)
      af[i] = *(const short8*)&As[(wr * 64 + i * 16 + l15) * 32 + q * 8];
#pragma unroll
    for (int j = 0; j < 4; j++)
      bf[j] = *(const short8*)&Bs[(wc * 64 + j * 16 + l15) * 32 + q * 8];
#pragma unroll
    for (int i = 0; i < 4; i++)
#pragma unroll
      for (int j = 0; j < 4; j++)
        acc[i][j] = __builtin_amdgcn_mfma_f32_16x16x32_bf16(af[i], bf[j], acc[i][j], 0, 0, 0);
    __syncthreads();
  }
  float bv[4];
#pragma unroll
  for (int j = 0; j < 4; j++) bv[j] = bias_s[C0 + wc * 64 + j * 16 + l15];
#pragma unroll
  for (int i = 0; i < 4; i++)
#pragma unroll
    for (int j = 0; j < 4; j++) {
      int col = C0 + wc * 64 + j * 16 + l15;
      long Rb = R0 + wr * 64 + i * 16 + q * 4;
#pragma unroll
      for (int r = 0; r < 4; r++)
        XP[(Rb + r) * NOUT + col] = acc[i][j][r] + bv[j];
    }
}

// ---------------------------------------------------------------- K1 slow GEMM
#define AS_STRIDE 40
__global__ __launch_bounds__(256, 2) void k1_gemm_slow(
    const float* __restrict__ X, const unsigned short* __restrict__ W,
    const float* __restrict__ bias_s, float* __restrict__ XP) {
  __shared__ unsigned short As[128 * AS_STRIDE];
  __shared__ unsigned short Bs[128 * 32];
  const int tid = threadIdx.x;
  const int lane = tid & 63, w = tid >> 6;
  const int q = lane >> 4, l15 = lane & 15;
  const int wr = w >> 1, wc = w & 1;
  const int nt = blockIdx.x, mt = blockIdx.y;
  const long R0 = (long)mt * 128;
  const int C0 = nt * 128;
  const int ar = tid >> 1, ahf = tid & 1;
  f32x4 acc[4][4];
#pragma unroll
  for (int i = 0; i < 4; i++)
#pragma unroll
    for (int j = 0; j < 4; j++) acc[i][j] = {0.f, 0.f, 0.f, 0.f};
  const float* arow = X + (R0 + ar) * D_IN;
  for (int it = 0; it < 31; it++) {
    int k0 = it * 32;
    unsigned pk[8];
#pragma unroll
    for (int c = 0; c < 4; c++) {
      int kc = k0 + ahf * 16 + c * 4;
      kc = (kc <= 964) ? kc : 964;
      f32x4 v = *(const f32x4*)(arow + kc);
      pk[c * 2 + 0] = pack2bf(v.x, v.y);
      pk[c * 2 + 1] = pack2bf(v.z, v.w);
    }
    unsigned short* adst = &As[ar * AS_STRIDE + ahf * 16];
    *(u32x4*)adst = (u32x4){pk[0], pk[1], pk[2], pk[3]};
    *(u32x4*)(adst + 8) = (u32x4){pk[4], pk[5], pk[6], pk[7]};
#pragma unroll
    for (int c = 0; c < 2; c++) {
      int idx = c * 256 + w * 64 + lane;
      int brow = idx >> 2, koff = (idx & 3) * 8;
      async_load16(W + (long)(C0 + brow) * KP + k0 + koff,
                   ((char*)Bs) + (c * 256 + w * 64) * 16);
    }
    __syncthreads();
    short8 af[4], bf[4];
#pragma unroll
    for (int i = 0; i < 4; i++)
      af[i] = *(const short8*)&As[(wr * 64 + i * 16 + l15) * AS_STRIDE + q * 8];
#pragma unroll
    for (int j = 0; j < 4; j++)
      bf[j] = *(const short8*)&Bs[(wc * 64 + j * 16 + l15) * 32 + q * 8];
#pragma unroll
    for (int i = 0; i < 4; i++)
#pragma unroll
      for (int j = 0; j < 4; j++)
        acc[i][j] = __builtin_amdgcn_mfma_f32_16x16x32_bf16(af[i], bf[j], acc[i][j], 0, 0, 0);
    __syncthreads();
  }
  float bv[4];
#pragma unroll
  for (int j = 0; j < 4; j++) bv[j] = bias_s[C0 + wc * 64 + j * 16 + l15];
#pragma unroll
  for (int i = 0; i < 4; i++)
#pragma unroll
    for (int j = 0; j < 4; j++) {
      int col = C0 + wc * 64 + j * 16 + l15;
      long Rb = R0 + wr * 64 + i * 16 + q * 4;
#pragma unroll
      for (int r = 0; r < 4; r++)
        XP[(Rb + r) * NOUT + col] = acc[i][j][r] + bv[j];
    }
}

// ---------------------------------------------------------------- K2 GRU scan
// 4 waves; wave w owns output cols [32w, 32w+32) as 2 col-groups of 16.
// Lane (q = lane>>4, b = lane&15): batch b, within-tile rows q*4..q*4+3.
__device__ __forceinline__ f32x4 gru_gate(f32x4 accR, f32x4 accZ, f32x4 accN,
                                          f32x4 gr, f32x4 gz, f32x4 gn,
                                          f32x4 bh2, f32x4 h) {
  f32x4 pr = gr + accR;
  f32x4 pz = gz + accZ;
  f32x4 er, ez;
#pragma unroll
  for (int i = 0; i < 4; i++) er[i] = exp2_(-pr[i]);
#pragma unroll
  for (int i = 0; i < 4; i++) ez[i] = exp2_(-pz[i]);
  f32x4 dr = er + 1.0f, dz = ez + 1.0f;
  f32x4 r, z;
#pragma unroll
  for (int i = 0; i < 4; i++) r[i] = rcp_(dr[i]);
#pragma unroll
  for (int i = 0; i < 4; i++) z[i] = rcp_(dz[i]);
  f32x4 pn = gn + r * (accN + bh2);
  f32x4 en;
#pragma unroll
  for (int i = 0; i < 4; i++) en[i] = exp2_(pn[i]);
  f32x4 dn = en + 1.0f, invn;
#pragma unroll
  for (int i = 0; i < 4; i++) invn[i] = rcp_(dn[i]);
  f32x4 n = 1.0f - 2.0f * invn;
  return n + z * (h - n);
}

#define PF 2
#define MFMA_BF16 __builtin_amdgcn_mfma_f32_16x16x32_bf16

// one GRU step; U = t&1 (compile-time). Reads Hl[U&1], writes Hl[(U^1)&1].
#define K2_STEP(U, REFILL)                                                    \
  {                                                                           \
    const unsigned short* hb = ((U) & 1) ? hrd1 : hrd0;                       \
    short8 f0 = *(const short8*)(hb + ch0);                                   \
    short8 f1 = *(const short8*)(hb + ch1);                                   \
    short8 f2 = *(const short8*)(hb + ch2);                                   \
    short8 f3 = *(const short8*)(hb + ch3);                                   \
    f32x4 cR0 = gg[0][0][U], cZ0 = gg[0][1][U], cN0 = gg[0][2][U];            \
    f32x4 cR1 = gg[1][0][U], cZ1 = gg[1][1][U], cN1 = gg[1][2][U];            \
    if (REFILL) {                                                             \
      gg[0][0][U] = *(const f32x4*)(gp);                                      \
      gg[0][1][U] = *(const f32x4*)(gp + 128);                                \
      gg[0][2][U] = *(const f32x4*)(gp + 256);                                \
      gg[1][0][U] = *(const f32x4*)(gp + 16);                                 \
      gg[1][1][U] = *(const f32x4*)(gp + 144);                                \
      gg[1][2][U] = *(const f32x4*)(gp + 272);                                \
      gp += gstep;                                                            \
    }                                                                         \
    const f32x4 zz = {0.f, 0.f, 0.f, 0.f};                                    \
    /* col-group 0: 3 chains, 4-deep (issue first) */                         \
    f32x4 aR0 = MFMA_BF16(afr[0][0][0], f0, zz, 0, 0, 0);                     \
    f32x4 aZ0 = MFMA_BF16(afr[0][1][0], f0, zz, 0, 0, 0);                     \
    f32x4 aN0 = MFMA_BF16(afr[0][2][0], f0, zz, 0, 0, 0);                     \
    aR0 = MFMA_BF16(afr[0][0][1], f1, aR0, 0, 0, 0);                          \
    aZ0 = MFMA_BF16(afr[0][1][1], f1, aZ0, 0, 0, 0);                          \
    aN0 = MFMA_BF16(afr[0][2][1], f1, aN0, 0, 0, 0);                          \
    aR0 = MFMA_BF16(afr[0][0][2], f2, aR0, 0, 0, 0);                          \
    aZ0 = MFMA_BF16(afr[0][1][2], f2, aZ0, 0, 0, 0);                          \
    aN0 = MFMA_BF16(afr[0][2][2], f2, aN0, 0, 0, 0);                          \
    aR0 = MFMA_BF16(afr[0][0][3], f3, aR0, 0, 0, 0);                          \
    aZ0 = MFMA_BF16(afr[0][1][3], f3, aZ0, 0, 0, 0);                          \
    aN0 = MFMA_BF16(afr[0][2][3], f3, aN0, 0, 0, 0);                          \
    /* col-group 1: 3 chains, 4-deep */                                       \
    f32x4 aR1 = MFMA_BF16(afr[1][0][0], f0, zz, 0, 0, 0);                     \
    f32x4 aZ1 = MFMA_BF16(afr[1][1][0], f0, zz, 0, 0, 0);                     \
    f32x4 aN1 = MFMA_BF16(afr[1][2][0], f0, zz, 0, 0, 0);                     \
    aR1 = MFMA_BF16(afr[1][0][1], f1, aR1, 0, 0, 0);                          \
    aZ1 = MFMA_BF16(afr[1][1][1], f1, aZ1, 0, 0, 0);                          \
    aN1 = MFMA_BF16(afr[1][2][1], f1, aN1, 0, 0, 0);                          \
    aR1 = MFMA_BF16(afr[1][0][2], f2, aR1, 0, 0, 0);                          \
    aZ1 = MFMA_BF16(afr[1][1][2], f2, aZ1, 0, 0, 0);                          \
    aN1 = MFMA_BF16(afr[1][2][2], f2, aN1, 0, 0, 0);                          \
    aR1 = MFMA_BF16(afr[1][0][3], f3, aR1, 0, 0, 0);                          \
    aZ1 = MFMA_BF16(afr[1][1][3], f3, aZ1, 0, 0, 0);                          \
    aN1 = MFMA_BF16(afr[1][2][3], f3, aN1, 0, 0, 0);                          \
    /* gate c0 overlaps c1's MFMA tail */                                     \
    f32x4 hn0 = gru_gate(aR0, aZ0, aN0, cR0, cZ0, cN0, bh20, h0);             \
    h0 = hn0;                                                                 \
    u32x2 hv0 = {pack2bf(hn0[0], hn0[1]), pack2bf(hn0[2], hn0[3])};           \
    *(u32x2*)(((U) & 1) ? hw0_b0 : hw0_b1) = hv0;                             \
    *(f32x4*)op = hn0;                                                        \
    f32x4 hn1 = gru_gate(aR1, aZ1, aN1, cR1, cZ1, cN1, bh21, h1);             \
    h1 = hn1;                                                                 \
    u32x2 hv1 = {pack2bf(hn1[0], hn1[1]), pack2bf(hn1[2], hn1[3])};           \
    *(u32x2*)(((U) & 1) ? hw1_b0 : hw1_b1) = hv1;                             \
    *(f32x4*)(op + 16) = hn1;                                                 \
    op += ostep;                                                              \
    wg_barrier_lds();                                                         \
  }

__global__ __launch_bounds__(256, 1) void k2_gru(
    const unsigned short* __restrict__ WHH, const float* __restrict__ XP,
    const float* __restrict__ bhh_f, const float* __restrict__ bhh_b,
    float* __restrict__ OUT) {
  __shared__ unsigned short Hl[2][16 * 128];      // double-buffered H (bf16, swizzled)

  const int tid = threadIdx.x;
  const int lane = tid & 63, w = tid >> 6;  // 4 waves; wave w: cols [32w,32w+32)
  const int q = lane >> 4, b = lane & 15;
  const int dir = blockIdx.x & 1, bg = blockIdx.x >> 1;
  const int j0 = w * 32 + q * 4;            // col-group 0 base col for this lane

  for (int i = tid; i < 2 * 16 * 128; i += 256) ((unsigned short*)Hl)[i] = 0;

  // resident Whh A-fragments: afr[cgroup][gate][kt]
  short8 afr[2][3][4];
#pragma unroll
  for (int c = 0; c < 2; c++)
#pragma unroll
    for (int g = 0; g < 3; g++)
#pragma unroll
      for (int kt = 0; kt < 4; kt++) {
        int row = dir * 384 + g * 128 + w * 32 + c * 16 + b;
        afr[c][g][kt] = *(const short8*)(WHH + (long)row * HID + kt * 32 + q * 8);
      }
  // only the n-gate hidden bias remains unfolded (multiplied by r)
  const float* bhh = dir ? bhh_b : bhh_f;
  f32x4 bh20 = (*(const f32x4*)(bhh + 256 + j0)) * (2.0f * LOG2E);
  f32x4 bh21 = (*(const f32x4*)(bhh + 256 + j0 + 16)) * (2.0f * LOG2E);

  // running pointers (consumer layout: batch row bg*16+b, col j0 + {0,16} + gate*128)
  const long gstep = dir ? -(long)NOUT : (long)NOUT;
  const long ostep = dir ? -256L : 256L;
  const int td0 = dir ? (TT - 1) : 0;
  const float* gp = XP + ((long)(bg * 16 + b) * TT + td0) * NOUT + dir * 384 + j0;
  float* op = OUT + ((long)(bg * 16 + b) * TT + td0) * 256 + dir * 128 + j0;

  // register ring prologue: gi(0..PF-1); gg[cgroup][gate][slot]
  f32x4 gg[2][3][PF];
#pragma unroll
  for (int u = 0; u < PF; u++) {
    gg[0][0][u] = *(const f32x4*)(gp);
    gg[0][1][u] = *(const f32x4*)(gp + 128);
    gg[0][2][u] = *(const f32x4*)(gp + 256);
    gg[1][0][u] = *(const f32x4*)(gp + 16);
    gg[1][1][u] = *(const f32x4*)(gp + 144);
    gg[1][2][u] = *(const f32x4*)(gp + 272);
    gp += gstep;
  }

  // hoisted LDS addresses (xor-swizzled 8-col chunks per batch row)
  const int ch0 = ((0 * 4 + q) ^ (b & 7)) * 8;
  const int ch1 = ((1 * 4 + q) ^ (b & 7)) * 8;
  const int ch2 = ((2 * 4 + q) ^ (b & 7)) * 8;
  const int ch3 = ((3 * 4 + q) ^ (b & 7)) * 8;
  // write chunks: cgroup c -> chunk 4w+2c+(q>>1), byte-half (q&1)*4
  const int cw0 = (((4 * w + 0 + (q >> 1)) ^ (b & 7)) * 8) + (q & 1) * 4;
  const int cw1 = (((4 * w + 2 + (q >> 1)) ^ (b & 7)) * 8) + (q & 1) * 4;
  const unsigned short* hrd0 = &Hl[0][b * 128];
  const unsigned short* hrd1 = &Hl[1][b * 128];
  unsigned short* hw0_b0 = &Hl[0][b * 128 + cw0];
  unsigned short* hw0_b1 = &Hl[1][b * 128 + cw0];
  unsigned short* hw1_b0 = &Hl[0][b * 128 + cw1];
  unsigned short* hw1_b1 = &Hl[1][b * 128 + cw1];

  f32x4 h0 = {0.f, 0.f, 0.f, 0.f};
  f32x4 h1 = {0.f, 0.f, 0.f, 0.f};
  __syncthreads();  // Hl zero-init visible

  // main loop refills gi(t+PF); epilogue pair: no refill (no OOB, no clamp)
  for (int t0 = 0; t0 < TT - PF; t0 += PF) {
    K2_STEP(0, 1)
    K2_STEP(1, 1)
  }
  K2_STEP(0, 0)
  K2_STEP(1, 0)
}

// ---------------------------------------------------------------- K3 LayerNorm
__global__ __launch_bounds__(256) void k3_ln(float* __restrict__ OUT,
                                             const float* __restrict__ lnw,
                                             const float* __restrict__ lnb) {
  const int tid = threadIdx.x, lane = tid & 63, w = tid >> 6;
  const long row = (long)blockIdx.x * 4 + w;
  float* p = OUT + row * 256 + lane * 4;
  f32x4 x = *(const f32x4*)p;
  float s = x[0] + x[1] + x[2] + x[3];
  float s2 = x[0] * x[0] + x[1] * x[1] + x[2] * x[2] + x[3] * x[3];
#pragma unroll
  for (int m = 1; m < 64; m <<= 1) {
    s += __shfl_xor(s, m, 64);
    s2 += __shfl_xor(s2, m, 64);
  }
  float mu = s * (1.0f / 256.0f);
  float var = (s2 - s * mu) * (1.0f / 255.0f);  // ddof=1
  var = fmaxf(var, 0.0f);
  float sig = fmaxf(sqrtf(var), 1e-6f);
  float inv = 1.0f / sig;
  f32x4 wv = *(const f32x4*)(lnw + lane * 4);
  f32x4 bv = *(const f32x4*)(lnb + lane * 4);
  f32x4 y;
#pragma unroll
  for (int i = 0; i < 4; i++) y[i] = (x[i] - mu) * inv * wv[i] + bv[i];
  *(f32x4*)p = y;
}

// ---------------------------------------------------------------- launch
extern "C" void kernel_launch(void* const* d_in, const int* in_sizes, int n_in,
                              void* d_out, int out_size, void* d_ws, size_t ws_size,
                              hipStream_t stream) {
  const float* x = (const float*)d_in[0];
  const float* wihf = (const float*)d_in[1];
  const float* whhf = (const float*)d_in[2];
  const float* bihf = (const float*)d_in[3];
  const float* bhhf = (const float*)d_in[4];
  const float* wihb = (const float*)d_in[5];
  const float* whhb = (const float*)d_in[6];
  const float* bihb = (const float*)d_in[7];
  const float* bhhb = (const float*)d_in[8];
  const float* lnw = (const float*)d_in[9];
  const float* lnb = (const float*)d_in[10];

  char* ws = (char*)d_ws;
  unsigned short* wih16 = (unsigned short*)ws;
  unsigned short* whh16 = (unsigned short*)(ws + WIH_BYTES);
  float* bias_s = (float*)(ws + WIH_BYTES + WHH_BYTES);
  float* out = (float*)d_out;

  const size_t need_fast = (size_t)BASE_OFF + XBF_BYTES + XP_BYTES;  // ~167.4 MB

  hipLaunchKernelGGL(k0_convert, dim3(768 + 96 + 1), dim3(256), 0, stream,
                     wihf, whhf, bihf, wihb, whhb, bihb, bhhf, bhhb,
                     wih16, whh16, bias_s);

  float* xp;
  if (ws_size >= need_fast) {
    unsigned short* xbf = (unsigned short*)(ws + BASE_OFF);
    xp = (float*)(ws + BASE_OFF + XBF_BYTES);
    hipLaunchKernelGGL(kx_convert, dim3(32768), dim3(256), 0, stream, x, xbf);
    hipLaunchKernelGGL(k1_gemm_fast, dim3(6, 256), dim3(256), 0, stream,
                       xbf, wih16, bias_s, xp);
  } else {
    xp = (float*)(ws + BASE_OFF);
    hipLaunchKernelGGL(k1_gemm_slow, dim3(6, 256), dim3(256), 0, stream,
                       x, wih16, bias_s, xp);
  }
  hipLaunchKernelGGL(k2_gru, dim3(8), dim3(256), 0, stream, whh16, xp, bhhf, bhhb, out);
  hipLaunchKernelGGL(k3_ln, dim3(8192), dim3(256), 0, stream, out, lnw, lnb);
}

// Round 4
// 676.969 us; speedup vs baseline: 1.0760x; 1.0760x over previous
//
#include <hip/hip_runtime.h>
#include <stdint.h>

// ---------------------------------------------------------------------------
// BiGRU + LayerNorm for MI355X (gfx950)
// kx: X fp32 -> bf16 (padded K 968->992), once
// k0: convert/scale weights to bf16 (log2e folded in; n-gate gets 2*log2e)
// k1: xp = x @ W_ih^T + b_ih  (m97-style: global_load_lds x16B both operands)
// k2: serial GRU scan, 8 WGs x 8 waves, register-ring gi prefetch (PF=4).
//     BARRIER FIX vs prior rounds: the old asm barrier carried a "memory"
//     clobber -> mayLoadStore -> SIInsertWaitcnts drains vmcnt(0) EVERY STEP
//     (per-step HBM latency on the critical path; explains why all prior
//     structural edits were neutral). New barrier = sched_barrier(0) pin +
//     lgkmcnt(0)-only wait + s_barrier BUILTIN (learn_hip m201/m218 pattern,
//     loads stay in flight across the barrier).
// k3: LayerNorm (unbiased std, clamp 1e-6), in place on d_out
// ---------------------------------------------------------------------------

#define LOG2E 1.4426950408889634f
#define TT 512
#define D_IN 968
#define KP 992
#define NOUT 768
#define HID 128

typedef __attribute__((ext_vector_type(8))) short short8;
typedef __attribute__((ext_vector_type(4))) float f32x4;
typedef __attribute__((ext_vector_type(4))) unsigned int u32x4;
typedef __attribute__((ext_vector_type(2))) unsigned int u32x2;

__device__ __forceinline__ unsigned short f2bf(float f) {
  unsigned u = __builtin_bit_cast(unsigned, f);
  u += 0x7FFFu + ((u >> 16) & 1u);   // RTNE
  return (unsigned short)(u >> 16);
}
__device__ __forceinline__ unsigned pack2bf(float a, float b) {
  return (unsigned)f2bf(a) | ((unsigned)f2bf(b) << 16);
}
__device__ __forceinline__ float exp2_(float x) { return __builtin_amdgcn_exp2f(x); }
__device__ __forceinline__ float rcp_(float x)  { return __builtin_amdgcn_rcpf(x); }

__device__ __forceinline__ void async_load16(const void* g, void* l) {
  __builtin_amdgcn_global_load_lds(
      (const __attribute__((address_space(1))) unsigned int*)g,
      (__attribute__((address_space(3))) unsigned int*)l, 16, 0, 0);
}

// Non-draining workgroup barrier: waits LDS ops only (lgkmcnt), leaves
// vmcnt (gi prefetch loads + OUT stores) in flight across the barrier.
// NO "memory" clobber (a memory clobber marks the asm mayLoadStore and
// SIInsertWaitcnts then drains vmcnt(0) before it). Ordering of the
// surrounding ds ops is pinned with sched_barrier(0).
__device__ __forceinline__ void wg_barrier_lds() {
  __builtin_amdgcn_sched_barrier(0);
  asm volatile("s_waitcnt lgkmcnt(0)");
  __builtin_amdgcn_s_barrier();
  __builtin_amdgcn_sched_barrier(0);
}

// ws layout
#define WIH_BYTES (NOUT * KP * 2)            // 1,523,712
#define WHH_BYTES (NOUT * HID * 2)           // 196,608
#define BIAS_BYTES 3072
#define BASE_OFF (WIH_BYTES + WHH_BYTES + BIAS_BYTES)  // 1,723,392 (256-aligned)
#define XBF_BYTES ((size_t)32768 * KP * 2)   // 65,011,712
#define XP_BYTES ((size_t)32768 * NOUT * 4)  // 100,663,296

// ---------------------------------------------------------------- kx: X->bf16
__global__ __launch_bounds__(256) void kx_convert(const float* __restrict__ X,
                                                  unsigned short* __restrict__ Xb) {
  const long row = blockIdx.x;
  const int t = threadIdx.x;  // chunk of 4 cols; 968/4 = 242 full chunks
  if (t < 242) {
    f32x4 v = *(const f32x4*)(X + row * D_IN + t * 4);
    u32x2 p = {pack2bf(v.x, v.y), pack2bf(v.z, v.w)};
    *(u32x2*)(Xb + row * KP + t * 4) = p;
  } else if (t < 248) {
    *(u32x2*)(Xb + row * KP + t * 4) = (u32x2){0, 0};  // zero-pad 968..991
  }
}

// ---------------------------------------------------------------- K0 convert
__global__ __launch_bounds__(256) void k0_convert(
    const float* __restrict__ wihf, const float* __restrict__ whhf,
    const float* __restrict__ bihf, const float* __restrict__ wihb,
    const float* __restrict__ whhb, const float* __restrict__ bihb,
    unsigned short* __restrict__ wih16, unsigned short* __restrict__ whh16,
    float* __restrict__ bias_s) {
  int blk = blockIdx.x, tid = threadIdx.x;
  if (blk < NOUT) {
    int n = blk;
    float sc = ((n % 384) < 256) ? LOG2E : 2.0f * LOG2E;
    const float* src = (n < 384) ? (wihf + (long)n * D_IN) : (wihb + (long)(n - 384) * D_IN);
    for (int c = 0; c < 4; c++) {
      int k = c * 256 + tid;
      if (k < KP) {
        float v = (k < D_IN) ? src[k] * sc : 0.0f;
        wih16[(long)n * KP + k] = f2bf(v);
      }
    }
  } else if (blk < NOUT + 96) {
    int e0 = ((blk - NOUT) * 256 + tid) * 4;
    for (int i = 0; i < 4; i++) {
      int e = e0 + i;
      int m = e >> 7, k = e & 127;
      float sc = ((m % 384) < 256) ? LOG2E : 2.0f * LOG2E;
      float v = (m < 384) ? whhf[m * HID + k] : whhb[(m - 384) * HID + k];
      whh16[e] = f2bf(v * sc);
    }
  } else {
    for (int c = 0; c < 3; c++) {
      int n = c * 256 + tid;
      if (n < NOUT) {
        float sc = ((n % 384) < 256) ? LOG2E : 2.0f * LOG2E;
        bias_s[n] = ((n < 384) ? bihf[n] : bihb[n - 384]) * sc;
      }
    }
  }
}

// ---------------------------------------------------------------- K1 fast GEMM
__global__ __launch_bounds__(256, 2) void k1_gemm_fast(
    const unsigned short* __restrict__ Xb, const unsigned short* __restrict__ W,
    const float* __restrict__ bias_s, float* __restrict__ XP) {
  __shared__ unsigned short As[128 * 32];
  __shared__ unsigned short Bs[128 * 32];

  const int tid = threadIdx.x;
  const int lane = tid & 63, w = tid >> 6;
  const int q = lane >> 4, l15 = lane & 15;
  const int wr = w >> 1, wc = w & 1;
  const int nt = blockIdx.x;   // 0..5 fast -> consecutive WGs share A-tile (L2)
  const int mt = blockIdx.y;   // 0..255
  const long R0 = (long)mt * 128;
  const int C0 = nt * 128;

  f32x4 acc[4][4];
#pragma unroll
  for (int i = 0; i < 4; i++)
#pragma unroll
    for (int j = 0; j < 4; j++) acc[i][j] = {0.f, 0.f, 0.f, 0.f};

  for (int it = 0; it < 31; it++) {
    const int k0 = it * 32;
#pragma unroll
    for (int c = 0; c < 2; c++) {
      int idx = c * 256 + w * 64 + lane;
      int row = idx >> 2, koff = (idx & 3) * 8;
      async_load16(Xb + (R0 + row) * KP + k0 + koff,
                   ((char*)As) + (c * 256 + w * 64) * 16);
      async_load16(W + (long)(C0 + row) * KP + k0 + koff,
                   ((char*)Bs) + (c * 256 + w * 64) * 16);
    }
    __syncthreads();  // drains vmcnt -> global_load_lds complete (m97 pattern)
    short8 af[4], bf[4];
#pragma unroll
    for (int i = 0; i < 4; i++)
      af[i] = *(const short8*)&As[(wr * 64 + i * 16 + l15) * 32 + q * 8];
#pragma unroll
    for (int j = 0; j < 4; j++)
      bf[j] = *(const short8*)&Bs[(wc * 64 + j * 16 + l15) * 32 + q * 8];
#pragma unroll
    for (int i = 0; i < 4; i++)
#pragma unroll
      for (int j = 0; j < 4; j++)
        acc[i][j] = __builtin_amdgcn_mfma_f32_16x16x32_bf16(af[i], bf[j], acc[i][j], 0, 0, 0);
    __syncthreads();
  }
  float bv[4];
#pragma unroll
  for (int j = 0; j < 4; j++) bv[j] = bias_s[C0 + wc * 64 + j * 16 + l15];
#pragma unroll
  for (int i = 0; i < 4; i++)
#pragma unroll
    for (int j = 0; j < 4; j++) {
      int col = C0 + wc * 64 + j * 16 + l15;
      long Rb = R0 + wr * 64 + i * 16 + q * 4;
#pragma unroll
      for (int r = 0; r < 4; r++)
        XP[(Rb + r) * NOUT + col] = acc[i][j][r] + bv[j];
    }
}

// ---------------------------------------------------------------- K1 slow GEMM
#define AS_STRIDE 40
__global__ __launch_bounds__(256, 2) void k1_gemm_slow(
    const float* __restrict__ X, const unsigned short* __restrict__ W,
    const float* __restrict__ bias_s, float* __restrict__ XP) {
  __shared__ unsigned short As[128 * AS_STRIDE];
  __shared__ unsigned short Bs[128 * 32];
  const int tid = threadIdx.x;
  const int lane = tid & 63, w = tid >> 6;
  const int q = lane >> 4, l15 = lane & 15;
  const int wr = w >> 1, wc = w & 1;
  const int nt = blockIdx.x, mt = blockIdx.y;
  const long R0 = (long)mt * 128;
  const int C0 = nt * 128;
  const int ar = tid >> 1, ahf = tid & 1;
  f32x4 acc[4][4];
#pragma unroll
  for (int i = 0; i < 4; i++)
#pragma unroll
    for (int j = 0; j < 4; j++) acc[i][j] = {0.f, 0.f, 0.f, 0.f};
  const float* arow = X + (R0 + ar) * D_IN;
  for (int it = 0; it < 31; it++) {
    int k0 = it * 32;
    unsigned pk[8];
#pragma unroll
    for (int c = 0; c < 4; c++) {
      int kc = k0 + ahf * 16 + c * 4;
      kc = (kc <= 964) ? kc : 964;
      f32x4 v = *(const f32x4*)(arow + kc);
      pk[c * 2 + 0] = pack2bf(v.x, v.y);
      pk[c * 2 + 1] = pack2bf(v.z, v.w);
    }
    unsigned short* adst = &As[ar * AS_STRIDE + ahf * 16];
    *(u32x4*)adst = (u32x4){pk[0], pk[1], pk[2], pk[3]};
    *(u32x4*)(adst + 8) = (u32x4){pk[4], pk[5], pk[6], pk[7]};
#pragma unroll
    for (int c = 0; c < 2; c++) {
      int idx = c * 256 + w * 64 + lane;
      int brow = idx >> 2, koff = (idx & 3) * 8;
      async_load16(W + (long)(C0 + brow) * KP + k0 + koff,
                   ((char*)Bs) + (c * 256 + w * 64) * 16);
    }
    __syncthreads();
    short8 af[4], bf[4];
#pragma unroll
    for (int i = 0; i < 4; i++)
      af[i] = *(const short8*)&As[(wr * 64 + i * 16 + l15) * AS_STRIDE + q * 8];
#pragma unroll
    for (int j = 0; j < 4; j++)
      bf[j] = *(const short8*)&Bs[(wc * 64 + j * 16 + l15) * 32 + q * 8];
#pragma unroll
    for (int i = 0; i < 4; i++)
#pragma unroll
      for (int j = 0; j < 4; j++)
        acc[i][j] = __builtin_amdgcn_mfma_f32_16x16x32_bf16(af[i], bf[j], acc[i][j], 0, 0, 0);
    __syncthreads();
  }
  float bv[4];
#pragma unroll
  for (int j = 0; j < 4; j++) bv[j] = bias_s[C0 + wc * 64 + j * 16 + l15];
#pragma unroll
  for (int i = 0; i < 4; i++)
#pragma unroll
    for (int j = 0; j < 4; j++) {
      int col = C0 + wc * 64 + j * 16 + l15;
      long Rb = R0 + wr * 64 + i * 16 + q * 4;
#pragma unroll
      for (int r = 0; r < 4; r++)
        XP[(Rb + r) * NOUT + col] = acc[i][j][r] + bv[j];
    }
}

// ---------------------------------------------------------------- K2 GRU scan
// 8 waves; wave w owns cols [16w,16w+16). Lane (q=lane>>4, b=lane&15):
// batch b, cols j0..j0+3 with j0 = w*16 + q*4. Register-ring gi (PF=4).
#define PF 4

__global__ __launch_bounds__(512) void k2_gru(
    const unsigned short* __restrict__ WHH, const float* __restrict__ XP,
    const float* __restrict__ bhh_f, const float* __restrict__ bhh_b,
    float* __restrict__ OUT) {
  __shared__ unsigned short Hl[2][16 * 128];      // double-buffered H (bf16, swizzled)

  const int tid = threadIdx.x;
  const int lane = tid & 63, w = tid >> 6;  // wave w owns cols [16w,16w+16)
  const int q = lane >> 4, b = lane & 15;
  const int dir = blockIdx.x & 1, bg = blockIdx.x >> 1;
  const int j0 = w * 16 + q * 4;

  for (int i = tid; i < 2 * 16 * 128; i += 512) ((unsigned short*)Hl)[i] = 0;

  // resident Whh A-fragments
  short8 afr[3][4];
#pragma unroll
  for (int g = 0; g < 3; g++)
#pragma unroll
    for (int kt = 0; kt < 4; kt++) {
      int row = dir * 384 + g * 128 + w * 16 + b;
      afr[g][kt] = *(const short8*)(WHH + (long)row * HID + kt * 32 + q * 8);
    }
  const float* bhh = dir ? bhh_b : bhh_f;
  f32x4 bh[3];
#pragma unroll
  for (int g = 0; g < 3; g++) {
    f32x4 t = *(const f32x4*)(bhh + g * 128 + j0);
    bh[g] = t * ((g < 2) ? LOG2E : 2.0f * LOG2E);
  }

  // direct consumer-layout gi base: batch row (bg*16+b), cols j0 (+0/128/256)
  const long gi_base = (long)(bg * 16 + b) * TT * NOUT + dir * 384 + j0;
  const long out_base = (long)(bg * 16 + b) * TT * 256 + dir * 128 + j0;

  // prologue: prefetch gi(0..PF-1) into the register ring
  f32x4 gR[PF], gZ[PF], gN[PF];
#pragma unroll
  for (int u = 0; u < PF; u++) {
    const int td = dir ? (TT - 1 - u) : u;
    const float* gb = XP + gi_base + (long)td * NOUT;
    gR[u] = *(const f32x4*)(gb);
    gZ[u] = *(const f32x4*)(gb + 128);
    gN[u] = *(const f32x4*)(gb + 256);
  }
  f32x4 h = {0.f, 0.f, 0.f, 0.f};
  __syncthreads();  // Hl zero-init visible; one full barrier pre-loop is fine

  for (int t0 = 0; t0 < TT; t0 += PF) {
#pragma unroll
    for (int u = 0; u < PF; u++) {
      const int t = t0 + u;
      const int cur = t & 1, nxt = cur ^ 1;
      const int td = dir ? (TT - 1 - t) : t;

      // 1) H B-fragments from Hl[cur] (issue first; MFMA waits on these)
      short8 bfr[4];
#pragma unroll
      for (int kt = 0; kt < 4; kt++) {
        int ch = ((kt * 4 + q) ^ (b & 7)) * 8;
        bfr[kt] = *(const short8*)&Hl[cur][b * 128 + ch];
      }
      // 2) MFMA: 3 independent chains of 4
      f32x4 accR = {0.f, 0.f, 0.f, 0.f};
      f32x4 accZ = {0.f, 0.f, 0.f, 0.f};
      f32x4 accN = {0.f, 0.f, 0.f, 0.f};
#pragma unroll
      for (int kt = 0; kt < 4; kt++) {
        accR = __builtin_amdgcn_mfma_f32_16x16x32_bf16(afr[0][kt], bfr[kt], accR, 0, 0, 0);
        accZ = __builtin_amdgcn_mfma_f32_16x16x32_bf16(afr[1][kt], bfr[kt], accZ, 0, 0, 0);
        accN = __builtin_amdgcn_mfma_f32_16x16x32_bf16(afr[2][kt], bfr[kt], accN, 0, 0, 0);
      }
      // 3) gate math (preacts pre-scaled by log2e / 2log2e); gi from ring slot u
      f32x4 hnew;
#pragma unroll
      for (int i = 0; i < 4; i++) {
        float pr = gR[u][i] + accR[i] + bh[0][i];
        float pz = gZ[u][i] + accZ[i] + bh[1][i];
        float r = rcp_(1.0f + exp2_(-pr));
        float z = rcp_(1.0f + exp2_(-pz));
        float pn = gN[u][i] + r * (accN[i] + bh[2][i]);
        float n = 1.0f - 2.0f * rcp_(exp2_(pn) + 1.0f);
        hnew[i] = n + z * (h[i] - n);
      }
      h = hnew;
      // 4) refill ring slot u with gi(t+PF)
      {
        int tn = t + PF;
        tn = (tn < TT) ? tn : (TT - 1);
        const int tdn = dir ? (TT - 1 - tn) : tn;
        const float* gb = XP + gi_base + (long)tdn * NOUT;
        gR[u] = *(const f32x4*)(gb);
        gZ[u] = *(const f32x4*)(gb + 128);
        gN[u] = *(const f32x4*)(gb + 256);
      }
      // 5) h' -> Hl[nxt] (bf16, swizzled) and global OUT (fp32)
      {
        int ch = ((j0 >> 3) ^ (b & 7)) * 8 + (j0 & 7);
        u32x2 hv = {pack2bf(hnew[0], hnew[1]), pack2bf(hnew[2], hnew[3])};
        *(u32x2*)&Hl[nxt][b * 128 + ch] = hv;
      }
      *(f32x4*)(OUT + out_base + (long)td * 256) = hnew;
      // 6) non-draining barrier: gi prefetch + OUT store stay in flight
      wg_barrier_lds();
    }
  }
}

// ---------------------------------------------------------------- K3 LayerNorm
__global__ __launch_bounds__(256) void k3_ln(float* __restrict__ OUT,
                                             const float* __restrict__ lnw,
                                             const float* __restrict__ lnb) {
  const int tid = threadIdx.x, lane = tid & 63, w = tid >> 6;
  const long row = (long)blockIdx.x * 4 + w;
  float* p = OUT + row * 256 + lane * 4;
  f32x4 x = *(const f32x4*)p;
  float s = x[0] + x[1] + x[2] + x[3];
  float s2 = x[0] * x[0] + x[1] * x[1] + x[2] * x[2] + x[3] * x[3];
#pragma unroll
  for (int m = 1; m < 64; m <<= 1) {
    s += __shfl_xor(s, m, 64);
    s2 += __shfl_xor(s2, m, 64);
  }
  float mu = s * (1.0f / 256.0f);
  float var = (s2 - s * mu) * (1.0f / 255.0f);  // ddof=1
  var = fmaxf(var, 0.0f);
  float sig = fmaxf(sqrtf(var), 1e-6f);
  float inv = 1.0f / sig;
  f32x4 wv = *(const f32x4*)(lnw + lane * 4);
  f32x4 bv = *(const f32x4*)(lnb + lane * 4);
  f32x4 y;
#pragma unroll
  for (int i = 0; i < 4; i++) y[i] = (x[i] - mu) * inv * wv[i] + bv[i];
  *(f32x4*)p = y;
}

// ---------------------------------------------------------------- launch
extern "C" void kernel_launch(void* const* d_in, const int* in_sizes, int n_in,
                              void* d_out, int out_size, void* d_ws, size_t ws_size,
                              hipStream_t stream) {
  const float* x = (const float*)d_in[0];
  const float* wihf = (const float*)d_in[1];
  const float* whhf = (const float*)d_in[2];
  const float* bihf = (const float*)d_in[3];
  const float* bhhf = (const float*)d_in[4];
  const float* wihb = (const float*)d_in[5];
  const float* whhb = (const float*)d_in[6];
  const float* bihb = (const float*)d_in[7];
  const float* bhhb = (const float*)d_in[8];
  const float* lnw = (const float*)d_in[9];
  const float* lnb = (const float*)d_in[10];

  char* ws = (char*)d_ws;
  unsigned short* wih16 = (unsigned short*)ws;
  unsigned short* whh16 = (unsigned short*)(ws + WIH_BYTES);
  float* bias_s = (float*)(ws + WIH_BYTES + WHH_BYTES);
  float* out = (float*)d_out;

  const size_t need_fast = (size_t)BASE_OFF + XBF_BYTES + XP_BYTES;  // ~167.4 MB

  hipLaunchKernelGGL(k0_convert, dim3(768 + 96 + 1), dim3(256), 0, stream,
                     wihf, whhf, bihf, wihb, whhb, bihb, wih16, whh16, bias_s);

  float* xp;
  if (ws_size >= need_fast) {
    unsigned short* xbf = (unsigned short*)(ws + BASE_OFF);
    xp = (float*)(ws + BASE_OFF + XBF_BYTES);
    hipLaunchKernelGGL(kx_convert, dim3(32768), dim3(256), 0, stream, x, xbf);
    hipLaunchKernelGGL(k1_gemm_fast, dim3(6, 256), dim3(256), 0, stream,
                       xbf, wih16, bias_s, xp);
  } else {
    xp = (float*)(ws + BASE_OFF);
    hipLaunchKernelGGL(k1_gemm_slow, dim3(6, 256), dim3(256), 0, stream,
                       x, wih16, bias_s, xp);
  }
  hipLaunchKernelGGL(k2_gru, dim3(8), dim3(512), 0, stream, whh16, xp, bhhf, bhhb, out);
  hipLaunchKernelGGL(k3_ln, dim3(8192), dim3(256), 0, stream, out, lnw, lnb);
}